// Round 11
// baseline (71.173 us; speedup 1.0000x reference)
//
#include <hip/hip_runtime.h>

// Fused attention block: B=4, S=2048, F=512, D=64
//  q = x@Wq + bq ; k = x@Wk + bk ; v = x@Wv + bv      (B,S,D)
//  logits = q@k^T / 8 + (1-mask)*-1e9 ; attn = softmax ; out = attn@v
//
// R11 = R8 + two surgical attn changes:
//  1. V-fragment loads hoisted ABOVE softmax and the asm fences. The
//     "memory"-clobber fences pin memory reads; in R8 the 8 V loads sat
//     right before the PV MFMAs -> exposed L2 latency every iteration.
//     vf[4][2] is written+read within one iteration with compile-time dt
//     indices only (no cross-iteration state -> no R9 localMem hazard).
//  2. s_setprio(1) around the QK and PV MFMA clusters (T5: barrier-free
//     multi-wave attn is the regime where this measured +4-7%).
//  launch_bounds(512,4) caps VGPR at 128 to keep 2 blocks/CU.
//  proj reverted to R8's proven 16-row/256-thr version (R10's 32-row was +2us).
//
// MFMA v_mfma_f32_16x16x32_bf16 fragment layouts (guide §3, m89/m91):
//   A: lane holds A[row = lane&15][k = (lane>>4)*8 + e], e=0..7
//   B: lane holds B[k = (lane>>4)*8 + e][col = lane&15]
//   C/D: lane holds D[row = (lane>>4)*4 + r][col = lane&15], r=0..3

typedef __attribute__((ext_vector_type(8))) short bhalf8;
typedef __attribute__((ext_vector_type(4))) float fx4;

#define MFMA(a, b, c) __builtin_amdgcn_mfma_f32_16x16x32_bf16((a), (b), (c), 0, 0, 0)

__device__ __forceinline__ short f2bf(float f) {
    union { float f; unsigned u; } v; v.f = f;
    unsigned r = (v.u + 0x7FFFu + ((v.u >> 16) & 1u)) >> 16;  // RNE
    return (short)r;
}

__device__ __forceinline__ unsigned cvt_pk_bf16(float lo, float hi) {
    unsigned r;
    asm("v_cvt_pk_bf16_f32 %0, %1, %2" : "=v"(r) : "v"(lo), "v"(hi));
    return r;
}

// Build B-fragment B[k0+e][col] (e=0..7) from row-major f32 W[512][64].
// 8 coalesced dword loads (16 lanes x consecutive cols) + 4 cvt_pk.
__device__ __forceinline__ bhalf8 wfrag(const float* __restrict__ W, int k0, int col) {
    union { unsigned u[4]; bhalf8 h; } r;
#pragma unroll
    for (int e2 = 0; e2 < 4; ++e2)
        r.u[e2] = cvt_pk_bf16(W[(k0 + 2 * e2) * 64 + col],
                              W[(k0 + 2 * e2 + 1) * 64 + col]);
    return r.h;
}

// ---- Kernel 1: QKV projection, conversion fused. 512 blocks x 256 thr ----
// Block = 16 x-rows (staged f32->bf16 in LDS); wave w = col-quarter w*16..+15
// for ALL of Q,K,V. Outputs: Qb,Kb bf16 [B*S][64]; Vt bf16 [B][64][2048]
// with within-64-key permutation phys = ((s>>4)&3) + (s&15)*4 (matches
// attn's packed-P physical layout).
__global__ __launch_bounds__(256) void proj_kernel(
    const float* __restrict__ x,
    const float* __restrict__ Wq, const float* __restrict__ bq,
    const float* __restrict__ Wk, const float* __restrict__ bk,
    const float* __restrict__ Wv, const float* __restrict__ bv,
    short* __restrict__ Qb, short* __restrict__ Kb, short* __restrict__ Vt)
{
    const int tid  = threadIdx.x;
    const int lane = tid & 63;
    const int wid  = tid >> 6;              // col-quarter 0..3
    const int g = lane >> 4, c = lane & 15;
    const int rowbase = blockIdx.x * 16;

    __shared__ __align__(16) short xs[16][520];   // pitch 1040B: 8 lanes per
                                                  // 4-bank window = LDS BW peak

    // ---- stage x rows -> bf16 LDS (coalesced float4, cvt_pk, 16B writes) ----
#pragma unroll
    for (int i = 0; i < 4; ++i) {
        const int id  = tid + i * 256;       // 0..1023 over (row, col-chunk)
        const int row = id >> 6;
        const int col8 = (id & 63) * 8;
        const float* xp = x + (size_t)(rowbase + row) * 512 + col8;
        const float4 f0 = *(const float4*)(xp);
        const float4 f1 = *(const float4*)(xp + 4);
        union { unsigned u[4]; uint4 v; } wv;
        wv.u[0] = cvt_pk_bf16(f0.x, f0.y);
        wv.u[1] = cvt_pk_bf16(f0.z, f0.w);
        wv.u[2] = cvt_pk_bf16(f1.x, f1.y);
        wv.u[3] = cvt_pk_bf16(f1.z, f1.w);
        *(uint4*)&xs[row][col8] = wv.v;
    }
    __syncthreads();

    const int col = wid * 16 + c;
    fx4 aq = (fx4){0.f, 0.f, 0.f, 0.f};
    fx4 ak = (fx4){0.f, 0.f, 0.f, 0.f};
    fx4 av = (fx4){0.f, 0.f, 0.f, 0.f};

#pragma unroll 4
    for (int ks = 0; ks < 16; ++ks) {
        const int k0 = ks * 32 + g * 8;
        const bhalf8 a = *(const bhalf8*)&xs[c][k0];   // A row = lane&15
        aq = MFMA(a, wfrag(Wq, k0, col), aq);
        ak = MFMA(a, wfrag(Wk, k0, col), ak);
        av = MFMA(a, wfrag(Wv, k0, col), av);
    }

    const float bq_ = bq[col], bk_ = bk[col], bv_ = bv[col];
#pragma unroll
    for (int r = 0; r < 4; ++r) {
        const int row = rowbase + g * 4 + r;           // D row = (lane>>4)*4+r
        Qb[row * 64 + col] = f2bf(aq[r] + bq_);
        Kb[row * 64 + col] = f2bf(ak[r] + bk_);
        const int s = row & 2047, b_ = row >> 11;
        const int sp = (s & ~63) | (((s >> 4) & 3) + (s & 15) * 4);
        Vt[((size_t)b_ * 64 + col) * 2048 + sp] = f2bf(av[r] + bv_);
    }
}

// ---- Kernel 2: flash attention. 8 waves/block, 16 q-rows/block, per-wave
// 256-key slice (4 iters x 64 keys), V-hoist + setprio, private online
// softmax, LDS combine. grid B*(S/16)=512 ----
__global__ __launch_bounds__(512, 4) void attn_kernel(const short* __restrict__ Qb,
                                                      const short* __restrict__ Kb,
                                                      const short* __restrict__ Vt,
                                                      const int* __restrict__ mask,
                                                      float* __restrict__ out) {
    const int tid  = threadIdx.x;
    const int wid  = tid >> 6;
    const int lane = tid & 63;
    const int g = lane >> 4, c = lane & 15;
    const int b     = blockIdx.x >> 7;
    const int qbase = (blockIdx.x & 127) << 4;
    const short* Qp = Qb + (size_t)(b * 2048 + qbase) * 64;
    const short* Kp = Kb + (size_t)b * 2048 * 64;
    const short* Vp = Vt + (size_t)b * 64 * 2048;
    const int*   mp = mask + b * 2048;

    const bhalf8 qf0 = *(const bhalf8*)(Qp + c * 64 + g * 8);
    const bhalf8 qf1 = *(const bhalf8*)(Qp + c * 64 + 32 + g * 8);

    float m_r[4], l_r[4];
    fx4 o[4];
#pragma unroll
    for (int r = 0; r < 4; ++r) { m_r[r] = -1e30f; l_r[r] = 0.f; }
#pragma unroll
    for (int dt = 0; dt < 4; ++dt) o[dt] = (fx4){0.f, 0.f, 0.f, 0.f};

    __shared__ float olds[8][16][65];                 // pad 65: no bank clash
    __shared__ float mlds[8][16];
    __shared__ float llds[8][16];
    __shared__ __align__(16) short Plds[8][16][72];   // pitch 144B = 9x16B

    for (int kt = 0; kt < 4; ++kt) {
        const int kb = (wid * 4 + kt) * 64;
        // ---- QK^T: four 16-key n-tiles, K=64 ----
        fx4 s[4];
        __builtin_amdgcn_s_setprio(1);
#pragma unroll
        for (int t = 0; t < 4; ++t) {
            const short* kp = Kp + (size_t)(kb + t * 16 + c) * 64 + g * 8;
            const bhalf8 kf0 = *(const bhalf8*)(kp);
            const bhalf8 kf1 = *(const bhalf8*)(kp + 32);
            fx4 z = (fx4){0.f, 0.f, 0.f, 0.f};
            z = MFMA(qf0, kf0, z);
            s[t] = MFMA(qf1, kf1, z);
        }
        __builtin_amdgcn_s_setprio(0);

        // ---- V-fragment loads HOISTED above softmax + fences ----
        // (fences below are memory-clobbers: loads placed after them cannot
        //  be hoisted by the compiler -- so we hoist in source. vf is
        //  compile-time-indexed within this iteration: registers, no scratch.)
        bhalf8 vf[4][2];
#pragma unroll
        for (int dt = 0; dt < 4; ++dt) {
            const short* vp = Vp + (size_t)(dt * 16 + c) * 2048 + kb + g * 8;
            vf[dt][0] = *(const bhalf8*)(vp);          // Vt is key-permuted
            vf[dt][1] = *(const bhalf8*)(vp + 32);     // to match packed P
        }

        // ---- mask + scale; online softmax (rows g*4+r, logical cols c+16t) ----
        float madd[4];
#pragma unroll
        for (int t = 0; t < 4; ++t) madd[t] = mp[kb + t * 16 + c] ? 0.f : -1e9f;
        float p[4][4], tm[4];
#pragma unroll
        for (int r = 0; r < 4; ++r) {
            tm[r] = -1e30f;
#pragma unroll
            for (int t = 0; t < 4; ++t) {
                p[t][r] = s[t][r] * 0.125f + madd[t];
                tm[r] = fmaxf(tm[r], p[t][r]);
            }
        }
#pragma unroll
        for (int r = 0; r < 4; ++r) {
            tm[r] = fmaxf(tm[r], __shfl_xor(tm[r], 1));
            tm[r] = fmaxf(tm[r], __shfl_xor(tm[r], 2));
            tm[r] = fmaxf(tm[r], __shfl_xor(tm[r], 4));
            tm[r] = fmaxf(tm[r], __shfl_xor(tm[r], 8));
        }
        float fac[4];
#pragma unroll
        for (int r = 0; r < 4; ++r) {
            const float nm = fmaxf(m_r[r], tm[r]);
            fac[r] = __expf(m_r[r] - nm);
            m_r[r] = nm;
            float rs = 0.f;
#pragma unroll
            for (int t = 0; t < 4; ++t) {
                p[t][r] = __expf(p[t][r] - nm);
                rs += p[t][r];
            }
            rs += __shfl_xor(rs, 1);
            rs += __shfl_xor(rs, 2);
            rs += __shfl_xor(rs, 4);
            rs += __shfl_xor(rs, 8);
            l_r[r] = l_r[r] * fac[r] + rs;
        }
#pragma unroll
        for (int dt = 0; dt < 4; ++dt)
#pragma unroll
            for (int r = 0; r < 4; ++r) o[dt][r] *= fac[r];

        // ---- P -> LDS, packed: phys col = c*4 + t (one b64 per row) ----
        // CROSS-LANE exchange: the asm pair below is load-bearing (R7 lesson).
        asm volatile("" ::: "memory");
#pragma unroll
        for (int r = 0; r < 4; ++r) {
            uint2 w0;
            w0.x = cvt_pk_bf16(p[0][r], p[1][r]);   // phys cols 4c, 4c+1
            w0.y = cvt_pk_bf16(p[2][r], p[3][r]);   // phys cols 4c+2, 4c+3
            *(uint2*)&Plds[wid][g * 4 + r][c * 4] = w0;
        }
        asm volatile("s_waitcnt lgkmcnt(0)" ::: "memory");
        const bhalf8 pa0 = *(const bhalf8*)(&Plds[wid][c][g * 8]);        // phys k
        const bhalf8 pa1 = *(const bhalf8*)(&Plds[wid][c][32 + g * 8]);
        __builtin_amdgcn_s_setprio(1);
#pragma unroll
        for (int dt = 0; dt < 4; ++dt) {
            o[dt] = MFMA(pa0, vf[dt][0], o[dt]);
            o[dt] = MFMA(pa1, vf[dt][1], o[dt]);
        }
        __builtin_amdgcn_s_setprio(0);
    }

    // ---- publish per-wave partial state ----
    if (c == 0) {
#pragma unroll
        for (int r = 0; r < 4; ++r) {
            mlds[wid][g * 4 + r] = m_r[r];
            llds[wid][g * 4 + r] = l_r[r];
        }
    }
#pragma unroll
    for (int dt = 0; dt < 4; ++dt)
#pragma unroll
        for (int r = 0; r < 4; ++r)
            olds[wid][g * 4 + r][dt * 16 + c] = o[dt][r];
    __syncthreads();

    // ---- cross-wave combine ----
    float* op = out + (size_t)(b * 2048 + qbase) * 64;
#pragma unroll
    for (int i = 0; i < 2; ++i) {
        const int idx = tid + i * 512;        // 0..1023 over (row,d)
        const int row = idx >> 6, d = idx & 63;
        float M = mlds[0][row];
#pragma unroll
        for (int w = 1; w < 8; ++w) M = fmaxf(M, mlds[w][row]);
        float num = 0.f, den = 0.f;
#pragma unroll
        for (int w = 0; w < 8; ++w) {
            const float wt = __expf(mlds[w][row] - M);
            num += wt * olds[w][row][d];
            den += wt * llds[w][row];
        }
        op[row * 64 + d] = num / den;
    }
}

extern "C" void kernel_launch(void* const* d_in, const int* in_sizes, int n_in,
                              void* d_out, int out_size, void* d_ws, size_t ws_size,
                              hipStream_t stream) {
    const float* x    = (const float*)d_in[0];
    const int*   mask = (const int*)d_in[1];
    const float* Wq   = (const float*)d_in[2];
    const float* bq   = (const float*)d_in[3];
    const float* Wk   = (const float*)d_in[4];
    const float* bk   = (const float*)d_in[5];
    const float* Wv   = (const float*)d_in[6];
    const float* bv   = (const float*)d_in[7];
    float* out = (float*)d_out;

    short* Qb = (short*)d_ws;                 // 4*2048*64
    short* Kb = Qb + 4 * 2048 * 64;           // 4*2048*64
    short* Vt = Kb + 4 * 2048 * 64;           // 4*2048*64 ([B][64][2048], key-permuted)

    proj_kernel<<<512, 256, 0, stream>>>(x, Wq, bq, Wk, bk, Wv, bv, Qb, Kb, Vt);
    attn_kernel<<<512, 512, 0, stream>>>(Qb, Kb, Vt, mask, out);
}

// Round 12
// 39.661 us; speedup vs baseline: 1.7945x; 1.7945x over previous
//
#include <hip/hip_runtime.h>

// Fused attention block: B=4, S=2048, F=512, D=64
//  q = x@Wq + bq ; k = x@Wk + bk ; v = x@Wv + bv      (B,S,D)
//  logits = q@k^T / 8 + (1-mask)*-1e9 ; attn = softmax ; out = attn@v
//
// R12 = R8 + ONE change: attn processes 2 q-tiles per wave (32 q-rows/block,
// grid 256). Latency-bound diagnosis (MfmaUtil 2.5%, VALUBusy 10%, occ 39%,
// attn ~30us vs ~8us L2 floor): double the independent work per wave (two
// softmax/PV chains share one K/V fragment load) and halve K/V L2 traffic.
// NO launch_bounds VGPR cap: R9/R11 regressions were spill caused by
// __launch_bounds__(512,4)'s 128-VGPR cap + added live state. Plain (512)
// lets VGPR grow (~180-200, 2 waves/SIMD = 1 block/CU = grid 256 exactly).
// Plds reused A-then-B: per-wave DS ops execute in order, so tile-A reads
// complete before tile-B writes. proj unchanged (R8's proven version).
//
// MFMA v_mfma_f32_16x16x32_bf16 fragment layouts (guide §3, m89/m91):
//   A: lane holds A[row = lane&15][k = (lane>>4)*8 + e], e=0..7
//   B: lane holds B[k = (lane>>4)*8 + e][col = lane&15]
//   C/D: lane holds D[row = (lane>>4)*4 + r][col = lane&15], r=0..3

typedef __attribute__((ext_vector_type(8))) short bhalf8;
typedef __attribute__((ext_vector_type(4))) float fx4;

#define MFMA(a, b, c) __builtin_amdgcn_mfma_f32_16x16x32_bf16((a), (b), (c), 0, 0, 0)

__device__ __forceinline__ short f2bf(float f) {
    union { float f; unsigned u; } v; v.f = f;
    unsigned r = (v.u + 0x7FFFu + ((v.u >> 16) & 1u)) >> 16;  // RNE
    return (short)r;
}

__device__ __forceinline__ unsigned cvt_pk_bf16(float lo, float hi) {
    unsigned r;
    asm("v_cvt_pk_bf16_f32 %0, %1, %2" : "=v"(r) : "v"(lo), "v"(hi));
    return r;
}

// Build B-fragment B[k0+e][col] (e=0..7) from row-major f32 W[512][64].
__device__ __forceinline__ bhalf8 wfrag(const float* __restrict__ W, int k0, int col) {
    union { unsigned u[4]; bhalf8 h; } r;
#pragma unroll
    for (int e2 = 0; e2 < 4; ++e2)
        r.u[e2] = cvt_pk_bf16(W[(k0 + 2 * e2) * 64 + col],
                              W[(k0 + 2 * e2 + 1) * 64 + col]);
    return r.h;
}

// ---- Kernel 1: QKV projection, conversion fused (R8 verbatim). ----
__global__ __launch_bounds__(256) void proj_kernel(
    const float* __restrict__ x,
    const float* __restrict__ Wq, const float* __restrict__ bq,
    const float* __restrict__ Wk, const float* __restrict__ bk,
    const float* __restrict__ Wv, const float* __restrict__ bv,
    short* __restrict__ Qb, short* __restrict__ Kb, short* __restrict__ Vt)
{
    const int tid  = threadIdx.x;
    const int lane = tid & 63;
    const int wid  = tid >> 6;              // col-quarter 0..3
    const int g = lane >> 4, c = lane & 15;
    const int rowbase = blockIdx.x * 16;

    __shared__ __align__(16) short xs[16][520];

#pragma unroll
    for (int i = 0; i < 4; ++i) {
        const int id  = tid + i * 256;
        const int row = id >> 6;
        const int col8 = (id & 63) * 8;
        const float* xp = x + (size_t)(rowbase + row) * 512 + col8;
        const float4 f0 = *(const float4*)(xp);
        const float4 f1 = *(const float4*)(xp + 4);
        union { unsigned u[4]; uint4 v; } wv;
        wv.u[0] = cvt_pk_bf16(f0.x, f0.y);
        wv.u[1] = cvt_pk_bf16(f0.z, f0.w);
        wv.u[2] = cvt_pk_bf16(f1.x, f1.y);
        wv.u[3] = cvt_pk_bf16(f1.z, f1.w);
        *(uint4*)&xs[row][col8] = wv.v;
    }
    __syncthreads();

    const int col = wid * 16 + c;
    fx4 aq = (fx4){0.f, 0.f, 0.f, 0.f};
    fx4 ak = (fx4){0.f, 0.f, 0.f, 0.f};
    fx4 av = (fx4){0.f, 0.f, 0.f, 0.f};

#pragma unroll 4
    for (int ks = 0; ks < 16; ++ks) {
        const int k0 = ks * 32 + g * 8;
        const bhalf8 a = *(const bhalf8*)&xs[c][k0];
        aq = MFMA(a, wfrag(Wq, k0, col), aq);
        ak = MFMA(a, wfrag(Wk, k0, col), ak);
        av = MFMA(a, wfrag(Wv, k0, col), av);
    }

    const float bq_ = bq[col], bk_ = bk[col], bv_ = bv[col];
#pragma unroll
    for (int r = 0; r < 4; ++r) {
        const int row = rowbase + g * 4 + r;
        Qb[row * 64 + col] = f2bf(aq[r] + bq_);
        Kb[row * 64 + col] = f2bf(ak[r] + bk_);
        const int s = row & 2047, b_ = row >> 11;
        const int sp = (s & ~63) | (((s >> 4) & 3) + (s & 15) * 4);
        Vt[((size_t)b_ * 64 + col) * 2048 + sp] = f2bf(av[r] + bv_);
    }
}

// ---- Kernel 2: flash attention. 8 waves/block, 32 q-rows/block (2 tiles
// per wave sharing K/V fragments), per-wave 256-key slice, private online
// softmax per tile, LDS combine. grid B*(S/32)=256 ----
__global__ __launch_bounds__(512) void attn_kernel(const short* __restrict__ Qb,
                                                   const short* __restrict__ Kb,
                                                   const short* __restrict__ Vt,
                                                   const int* __restrict__ mask,
                                                   float* __restrict__ out) {
    const int tid  = threadIdx.x;
    const int wid  = tid >> 6;
    const int lane = tid & 63;
    const int g = lane >> 4, c = lane & 15;
    const int b     = blockIdx.x >> 6;          // 64 blocks per batch
    const int qbase = (blockIdx.x & 63) << 5;   // 32 rows per block
    const short* Qp = Qb + (size_t)(b * 2048 + qbase) * 64;
    const short* Kp = Kb + (size_t)b * 2048 * 64;
    const short* Vp = Vt + (size_t)b * 64 * 2048;
    const int*   mp = mask + b * 2048;

    // Q fragments: tile A = rows 0..15, tile B = rows 16..31
    const bhalf8 qfA0 = *(const bhalf8*)(Qp + c * 64 + g * 8);
    const bhalf8 qfA1 = *(const bhalf8*)(Qp + c * 64 + 32 + g * 8);
    const bhalf8 qfB0 = *(const bhalf8*)(Qp + (16 + c) * 64 + g * 8);
    const bhalf8 qfB1 = *(const bhalf8*)(Qp + (16 + c) * 64 + 32 + g * 8);

    float mA[4], lA[4], mB[4], lB[4];
    fx4 oA[4], oB[4];
#pragma unroll
    for (int r = 0; r < 4; ++r) { mA[r] = -1e30f; lA[r] = 0.f; mB[r] = -1e30f; lB[r] = 0.f; }
#pragma unroll
    for (int dt = 0; dt < 4; ++dt) { oA[dt] = (fx4){0.f, 0.f, 0.f, 0.f}; oB[dt] = (fx4){0.f, 0.f, 0.f, 0.f}; }

    __shared__ float olds[8][32][65];                 // 66.6 KB
    __shared__ float mlds[8][32];
    __shared__ float llds[8][32];
    __shared__ __align__(16) short Plds[8][16][72];   // reused A then B

    for (int kt = 0; kt < 4; ++kt) {
        const int kb = (wid * 4 + kt) * 64;

        // ---- QK^T for BOTH tiles, sharing the K fragments ----
        fx4 sA[4], sB[4];
#pragma unroll
        for (int t = 0; t < 4; ++t) {
            const short* kp = Kp + (size_t)(kb + t * 16 + c) * 64 + g * 8;
            const bhalf8 kf0 = *(const bhalf8*)(kp);
            const bhalf8 kf1 = *(const bhalf8*)(kp + 32);
            fx4 zA = (fx4){0.f, 0.f, 0.f, 0.f};
            zA = MFMA(qfA0, kf0, zA);
            sA[t] = MFMA(qfA1, kf1, zA);
            fx4 zB = (fx4){0.f, 0.f, 0.f, 0.f};
            zB = MFMA(qfB0, kf0, zB);
            sB[t] = MFMA(qfB1, kf1, zB);
        }

        // ---- V fragments, loaded ONCE for both tiles (above the fences) ----
        bhalf8 vf[4][2];
#pragma unroll
        for (int dt = 0; dt < 4; ++dt) {
            const short* vp = Vp + (size_t)(dt * 16 + c) * 2048 + kb + g * 8;
            vf[dt][0] = *(const bhalf8*)(vp);          // Vt is key-permuted
            vf[dt][1] = *(const bhalf8*)(vp + 32);     // to match packed P
        }

        float madd[4];
#pragma unroll
        for (int t = 0; t < 4; ++t) madd[t] = mp[kb + t * 16 + c] ? 0.f : -1e9f;

        // ================= tile A: softmax + exchange + PV =================
        {
            float p[4][4], tm[4];
#pragma unroll
            for (int r = 0; r < 4; ++r) {
                tm[r] = -1e30f;
#pragma unroll
                for (int t = 0; t < 4; ++t) {
                    p[t][r] = sA[t][r] * 0.125f + madd[t];
                    tm[r] = fmaxf(tm[r], p[t][r]);
                }
            }
#pragma unroll
            for (int r = 0; r < 4; ++r) {
                tm[r] = fmaxf(tm[r], __shfl_xor(tm[r], 1));
                tm[r] = fmaxf(tm[r], __shfl_xor(tm[r], 2));
                tm[r] = fmaxf(tm[r], __shfl_xor(tm[r], 4));
                tm[r] = fmaxf(tm[r], __shfl_xor(tm[r], 8));
            }
            float fac[4];
#pragma unroll
            for (int r = 0; r < 4; ++r) {
                const float nm = fmaxf(mA[r], tm[r]);
                fac[r] = __expf(mA[r] - nm);
                mA[r] = nm;
                float rs = 0.f;
#pragma unroll
                for (int t = 0; t < 4; ++t) {
                    p[t][r] = __expf(p[t][r] - nm);
                    rs += p[t][r];
                }
                rs += __shfl_xor(rs, 1);
                rs += __shfl_xor(rs, 2);
                rs += __shfl_xor(rs, 4);
                rs += __shfl_xor(rs, 8);
                lA[r] = lA[r] * fac[r] + rs;
            }
#pragma unroll
            for (int dt = 0; dt < 4; ++dt)
#pragma unroll
                for (int r = 0; r < 4; ++r) oA[dt][r] *= fac[r];

            asm volatile("" ::: "memory");
#pragma unroll
            for (int r = 0; r < 4; ++r) {
                uint2 w0;
                w0.x = cvt_pk_bf16(p[0][r], p[1][r]);
                w0.y = cvt_pk_bf16(p[2][r], p[3][r]);
                *(uint2*)&Plds[wid][g * 4 + r][c * 4] = w0;
            }
            asm volatile("s_waitcnt lgkmcnt(0)" ::: "memory");
            const bhalf8 pa0 = *(const bhalf8*)(&Plds[wid][c][g * 8]);
            const bhalf8 pa1 = *(const bhalf8*)(&Plds[wid][c][32 + g * 8]);
#pragma unroll
            for (int dt = 0; dt < 4; ++dt) {
                oA[dt] = MFMA(pa0, vf[dt][0], oA[dt]);
                oA[dt] = MFMA(pa1, vf[dt][1], oA[dt]);
            }
        }

        // ================= tile B: softmax + exchange + PV =================
        // (Plds reuse is safe: per-wave DS ops execute in order, so tile-A
        //  reads complete before tile-B writes to the same addresses.)
        {
            float p[4][4], tm[4];
#pragma unroll
            for (int r = 0; r < 4; ++r) {
                tm[r] = -1e30f;
#pragma unroll
                for (int t = 0; t < 4; ++t) {
                    p[t][r] = sB[t][r] * 0.125f + madd[t];
                    tm[r] = fmaxf(tm[r], p[t][r]);
                }
            }
#pragma unroll
            for (int r = 0; r < 4; ++r) {
                tm[r] = fmaxf(tm[r], __shfl_xor(tm[r], 1));
                tm[r] = fmaxf(tm[r], __shfl_xor(tm[r], 2));
                tm[r] = fmaxf(tm[r], __shfl_xor(tm[r], 4));
                tm[r] = fmaxf(tm[r], __shfl_xor(tm[r], 8));
            }
            float fac[4];
#pragma unroll
            for (int r = 0; r < 4; ++r) {
                const float nm = fmaxf(mB[r], tm[r]);
                fac[r] = __expf(mB[r] - nm);
                mB[r] = nm;
                float rs = 0.f;
#pragma unroll
                for (int t = 0; t < 4; ++t) {
                    p[t][r] = __expf(p[t][r] - nm);
                    rs += p[t][r];
                }
                rs += __shfl_xor(rs, 1);
                rs += __shfl_xor(rs, 2);
                rs += __shfl_xor(rs, 4);
                rs += __shfl_xor(rs, 8);
                lB[r] = lB[r] * fac[r] + rs;
            }
#pragma unroll
            for (int dt = 0; dt < 4; ++dt)
#pragma unroll
                for (int r = 0; r < 4; ++r) oB[dt][r] *= fac[r];

            asm volatile("" ::: "memory");
#pragma unroll
            for (int r = 0; r < 4; ++r) {
                uint2 w0;
                w0.x = cvt_pk_bf16(p[0][r], p[1][r]);
                w0.y = cvt_pk_bf16(p[2][r], p[3][r]);
                *(uint2*)&Plds[wid][g * 4 + r][c * 4] = w0;
            }
            asm volatile("s_waitcnt lgkmcnt(0)" ::: "memory");
            const bhalf8 pa0 = *(const bhalf8*)(&Plds[wid][c][g * 8]);
            const bhalf8 pa1 = *(const bhalf8*)(&Plds[wid][c][32 + g * 8]);
#pragma unroll
            for (int dt = 0; dt < 4; ++dt) {
                oB[dt] = MFMA(pa0, vf[dt][0], oB[dt]);
                oB[dt] = MFMA(pa1, vf[dt][1], oB[dt]);
            }
        }
    }

    // ---- publish per-wave partial state (rows 0..15 = A, 16..31 = B) ----
    if (c == 0) {
#pragma unroll
        for (int r = 0; r < 4; ++r) {
            mlds[wid][g * 4 + r]      = mA[r];
            llds[wid][g * 4 + r]      = lA[r];
            mlds[wid][16 + g * 4 + r] = mB[r];
            llds[wid][16 + g * 4 + r] = lB[r];
        }
    }
#pragma unroll
    for (int dt = 0; dt < 4; ++dt)
#pragma unroll
        for (int r = 0; r < 4; ++r) {
            olds[wid][g * 4 + r][dt * 16 + c]      = oA[dt][r];
            olds[wid][16 + g * 4 + r][dt * 16 + c] = oB[dt][r];
        }
    __syncthreads();

    // ---- cross-wave combine (2048 outputs, 4 per thread) ----
    float* op = out + (size_t)(b * 2048 + qbase) * 64;
#pragma unroll
    for (int i = 0; i < 4; ++i) {
        const int idx = tid + i * 512;        // 0..2047 over (row,d)
        const int row = idx >> 6, d = idx & 63;
        float M = mlds[0][row];
#pragma unroll
        for (int w = 1; w < 8; ++w) M = fmaxf(M, mlds[w][row]);
        float num = 0.f, den = 0.f;
#pragma unroll
        for (int w = 0; w < 8; ++w) {
            const float wt = __expf(mlds[w][row] - M);
            num += wt * olds[w][row][d];
            den += wt * llds[w][row];
        }
        op[row * 64 + d] = num / den;
    }
}

extern "C" void kernel_launch(void* const* d_in, const int* in_sizes, int n_in,
                              void* d_out, int out_size, void* d_ws, size_t ws_size,
                              hipStream_t stream) {
    const float* x    = (const float*)d_in[0];
    const int*   mask = (const int*)d_in[1];
    const float* Wq   = (const float*)d_in[2];
    const float* bq   = (const float*)d_in[3];
    const float* Wk   = (const float*)d_in[4];
    const float* bk   = (const float*)d_in[5];
    const float* Wv   = (const float*)d_in[6];
    const float* bv   = (const float*)d_in[7];
    float* out = (float*)d_out;

    short* Qb = (short*)d_ws;                 // 4*2048*64
    short* Kb = Qb + 4 * 2048 * 64;           // 4*2048*64
    short* Vt = Kb + 4 * 2048 * 64;           // 4*2048*64 ([B][64][2048], key-permuted)

    proj_kernel<<<512, 256, 0, stream>>>(x, Wq, bq, Wk, bk, Wv, bv, Qb, Kb, Vt);
    attn_kernel<<<256, 512, 0, stream>>>(Qb, Kb, Vt, mask, out);
}